// Round 1
// baseline (1194.685 us; speedup 1.0000x reference)
//
#include <hip/hip_runtime.h>
#include <hip/hip_bf16.h>

// Problem constants (B=4, L=2048, D=1024, H=16, HD=64, K=32, MAXLEN=2048)
#define BB 4
#define LL 2048
#define DD 1024
#define HH 16
#define HD 64
#define KK 32

// ---------------------------------------------------------------------------
// Generic 128x128-tile fp32 GEMM, 256 threads, 8x8 micro-tile (split as 8x2x4
// so LDS B-reads are 2-way-conflict float4s). C = A(MxK) @ B(KxN) + bias[col].
// MODE 0: scatter-write into V2[h][n][b*64+kk]  (row=(b,n), col=(h,kk))
// MODE 1: linear write out[row*N + col]
// ---------------------------------------------------------------------------
template <int MODE>
__global__ __launch_bounds__(256) void gemm128(const float* __restrict__ A,
                                               const float* __restrict__ B,
                                               const float* __restrict__ bias,
                                               float* __restrict__ C,
                                               int M, int N, int K) {
    __shared__ float As[16][128];
    __shared__ float Bs[16][128];
    const int tid = threadIdx.x;
    const int tx = tid & 15;        // 16 col groups
    const int ty = tid >> 4;        // 16 row groups
    const int row0 = blockIdx.y * 128;
    const int col0 = blockIdx.x * 128;

    float acc[8][2][4];
#pragma unroll
    for (int i = 0; i < 8; ++i)
#pragma unroll
        for (int q = 0; q < 2; ++q)
#pragma unroll
            for (int j = 0; j < 4; ++j) acc[i][q][j] = 0.f;

    for (int k0 = 0; k0 < K; k0 += 16) {
        // Load A tile (128 rows x 16 k) as float4 per thread, 2 iters.
#pragma unroll
        for (int p = 0; p < 2; ++p) {
            int f = tid + 256 * p;          // 0..511 float4s
            int m = f >> 2;                 // 0..127
            int k4 = (f & 3) << 2;          // 0,4,8,12
            float4 t = *(const float4*)&A[(size_t)(row0 + m) * K + k0 + k4];
            As[k4 + 0][m] = t.x;
            As[k4 + 1][m] = t.y;
            As[k4 + 2][m] = t.z;
            As[k4 + 3][m] = t.w;
        }
        // Load B tile (16 k x 128 cols) as float4, 2 iters.
#pragma unroll
        for (int p = 0; p < 2; ++p) {
            int f = tid + 256 * p;          // 0..511
            int kb = f >> 5;                // 0..15
            int n4 = (f & 31) << 2;         // 0..124
            *(float4*)&Bs[kb][n4] =
                *(const float4*)&B[(size_t)(k0 + kb) * N + col0 + n4];
        }
        __syncthreads();
#pragma unroll
        for (int k = 0; k < 16; ++k) {
            float a[8];
#pragma unroll
            for (int i = 0; i < 8; ++i) a[i] = As[k][(ty << 3) + i];
#pragma unroll
            for (int q = 0; q < 2; ++q) {
                float4 vb = *(const float4*)&Bs[k][q * 64 + (tx << 2)];
                float br[4] = {vb.x, vb.y, vb.z, vb.w};
#pragma unroll
                for (int i = 0; i < 8; ++i)
#pragma unroll
                    for (int j = 0; j < 4; ++j) acc[i][q][j] += a[i] * br[j];
            }
        }
        __syncthreads();
    }

    // Epilogue
#pragma unroll
    for (int i = 0; i < 8; ++i) {
        int r = row0 + (ty << 3) + i;
#pragma unroll
        for (int q = 0; q < 2; ++q) {
            int c0 = col0 + q * 64 + (tx << 2);
            float4 bb = *(const float4*)&bias[c0];
            float4 v;
            v.x = acc[i][q][0] + bb.x;
            v.y = acc[i][q][1] + bb.y;
            v.z = acc[i][q][2] + bb.z;
            v.w = acc[i][q][3] + bb.w;
            if (MODE == 0) {
                // r = b*2048 + n ; c = h*64 + kk -> V2[h][n][b*64+kk]
                int b = r >> 11, n = r & 2047;
                int h = c0 >> 6, kk = c0 & 63;
                *(float4*)&C[(((size_t)h * LL + n) << 8) + (b << 6) + kk] = v;
            } else {
                *(float4*)&C[(size_t)r * N + c0] = v;
            }
        }
    }
}

// ---------------------------------------------------------------------------
// Softmax denominators: denom[h][l] = sum_n exp(sum_k r1[h][l][k]*r2[h][k][n])
// Scores are tiny (|s| << 1) so exp without max-subtraction is exact softmax.
// One workgroup = 64 rows, 4 threads/row splitting the n range.
// ---------------------------------------------------------------------------
__global__ __launch_bounds__(256) void score_stats(const float* __restrict__ r1,
                                                   const float* __restrict__ r2,
                                                   float* __restrict__ denom) {
    __shared__ float Ls[32][256];
    const int tid = threadIdx.x;
    const int h = blockIdx.y;
    const int l0 = blockIdx.x * 64;
    const int row = tid >> 2;  // 0..63
    const int sub = tid & 3;   // n-split
    const int l = l0 + row;

    float r1r[32];
#pragma unroll
    for (int k4 = 0; k4 < 8; ++k4) {
        float4 t = *(const float4*)&r1[((size_t)h * LL + l) * KK + (k4 << 2)];
        r1r[k4 * 4 + 0] = t.x;
        r1r[k4 * 4 + 1] = t.y;
        r1r[k4 * 4 + 2] = t.z;
        r1r[k4 * 4 + 3] = t.w;
    }

    float sum = 0.f;
    for (int n0 = 0; n0 < LL; n0 += 256) {
        __syncthreads();
#pragma unroll
        for (int p = 0; p < 8; ++p) {
            int f = tid + 256 * p;       // 0..2047 float4s
            int k = f >> 6;              // 0..31
            int j4 = (f & 63) << 2;      // 0..252
            *(float4*)&Ls[k][j4] =
                *(const float4*)&r2[((size_t)h * KK + k) * LL + n0 + j4];
        }
        __syncthreads();
        for (int jj = 0; jj < 64; ++jj) {
            int j = (jj << 2) + sub;
            float s = 0.f;
#pragma unroll
            for (int k = 0; k < 32; ++k) s += r1r[k] * Ls[k][j];
            sum += __expf(s);
        }
    }
    // reduce the 4 sub-partials (adjacent lanes)
    sum += __shfl_xor(sum, 1);
    sum += __shfl_xor(sum, 2);
    if (sub == 0) denom[h * LL + l] = sum;
}

// ---------------------------------------------------------------------------
// y = softmax(scores) @ V, fused: recompute scores per n-chunk (K=32 is cheap),
// p = exp(s) * (1/denom[row]), accumulate over V2[h][n][0..255].
// Tile: 64 l-rows x 256 cols (all b*HD), n-chunks of 32.
// Writes y[b][l][h][hd].
// ---------------------------------------------------------------------------
__global__ __launch_bounds__(256) void attn_pv(const float* __restrict__ r1,
                                               const float* __restrict__ r2,
                                               const float* __restrict__ denom,
                                               const float* __restrict__ V2,
                                               float* __restrict__ y) {
    __shared__ float r1s[64][33];   // +1 pad: score loop reads stride-33 -> 2-way
    __shared__ float r2s[32][32];
    __shared__ float Ps[32][64];
    __shared__ float V2s[32][256];
    __shared__ float invd[64];
    const int tid = threadIdx.x;
    const int h = blockIdx.y;
    const int l0 = blockIdx.x * 64;
    const int tx = tid & 15;   // col group
    const int ty = tid >> 4;   // row group (0..15), 4 rows each

    // r1 tile (64 x 32)
#pragma unroll
    for (int p = 0; p < 8; ++p) {
        int i = tid + 256 * p;
        int row = i >> 5, k = i & 31;
        r1s[row][k] = r1[((size_t)h * LL + l0 + row) * KK + k];
    }
    if (tid < 64) invd[tid] = 1.0f / denom[h * LL + l0 + tid];

    float acc[4][4][4];
#pragma unroll
    for (int i = 0; i < 4; ++i)
#pragma unroll
        for (int jj = 0; jj < 4; ++jj)
#pragma unroll
            for (int j = 0; j < 4; ++j) acc[i][jj][j] = 0.f;

    for (int n0 = 0; n0 < LL; n0 += 32) {
        __syncthreads();
        // r2 chunk (32k x 32n): one float4 per thread
        {
            int k = tid >> 3;
            int j4 = (tid & 7) << 2;
            *(float4*)&r2s[k][j4] =
                *(const float4*)&r2[((size_t)h * KK + k) * LL + n0 + j4];
        }
        // V2 chunk (32n x 256c)
#pragma unroll
        for (int p = 0; p < 8; ++p) {
            int f = tid + 256 * p;       // 0..2047 float4s
            int n = f >> 6;              // 0..31
            int c4 = (f & 63) << 2;
            *(float4*)&V2s[n][c4] =
                *(const float4*)&V2[(((size_t)h * LL) + n0 + n) * 256 + c4];
        }
        __syncthreads();
        // P = exp(S)/denom : 64 rows x 32 n, 8 per thread
#pragma unroll
        for (int q = 0; q < 8; ++q) {
            int idx = tid + 256 * q;
            int row = idx & 63, n = idx >> 6;
            float s = 0.f;
#pragma unroll
            for (int k = 0; k < 32; ++k) s += r1s[row][k] * r2s[k][n];
            Ps[n][row] = __expf(s) * invd[row];
        }
        __syncthreads();
        // rank-32 update
#pragma unroll
        for (int n = 0; n < 32; ++n) {
            float4 pv = *(const float4*)&Ps[n][ty << 2];
            float pr[4] = {pv.x, pv.y, pv.z, pv.w};
#pragma unroll
            for (int jj = 0; jj < 4; ++jj) {
                float4 v = *(const float4*)&V2s[n][jj * 64 + (tx << 2)];
                float vr[4] = {v.x, v.y, v.z, v.w};
#pragma unroll
                for (int i = 0; i < 4; ++i)
#pragma unroll
                    for (int j = 0; j < 4; ++j) acc[i][jj][j] += pr[i] * vr[j];
            }
        }
    }
    // y[b][l][h][hd] ; col = jj*64 + tx*4 + j -> b=jj, hd=tx*4+j
#pragma unroll
    for (int i = 0; i < 4; ++i) {
        int l = l0 + (ty << 2) + i;
#pragma unroll
        for (int jj = 0; jj < 4; ++jj) {
            float4 v;
            v.x = acc[i][jj][0];
            v.y = acc[i][jj][1];
            v.z = acc[i][jj][2];
            v.w = acc[i][jj][3];
            *(float4*)&y[((((size_t)jj * LL + l) * HH) + h) * HD + (tx << 2)] = v;
        }
    }
}

extern "C" void kernel_launch(void* const* d_in, const int* in_sizes, int n_in,
                              void* d_out, int out_size, void* d_ws, size_t ws_size,
                              hipStream_t stream) {
    const float* inputs_kv = (const float*)d_in[1];
    const float* Wv = (const float*)d_in[2];   // (D, H*HD) row-major
    const float* bv = (const float*)d_in[3];   // (H*HD)
    const float* r1 = (const float*)d_in[4];   // (H, L, K)
    const float* r2 = (const float*)d_in[5];   // (H, K, L)
    const float* Wo = (const float*)d_in[6];   // (H*HD, D) row-major
    const float* bo = (const float*)d_in[7];   // (D)
    float* out = (float*)d_out;

    char* ws = (char*)d_ws;
    float* V2 = (float*)ws;                                        // 32 MB: [H][L][B*HD]
    float* denom = (float*)(ws + (size_t)32 * 1024 * 1024);        // 128 KB
    float* y = (float*)(ws + (size_t)32 * 1024 * 1024 + 256 * 1024);  // 32 MB: [B][L][H][HD]

    dim3 blk(256);
    // Stage 1: V = inputs_kv @ Wv + bv, scattered to [h][n][b*64+hd]
    gemm128<0><<<dim3(8, 64), blk, 0, stream>>>(inputs_kv, Wv, bv, V2,
                                                BB * LL, HH * HD, DD);
    // Stage 2: softmax denominators per (h, l) row
    score_stats<<<dim3(32, 16), blk, 0, stream>>>(r1, r2, denom);
    // Stage 3: y = attn @ V (fused score recompute + normalize)
    attn_pv<<<dim3(32, 16), blk, 0, stream>>>(r1, r2, denom, V2, y);
    // Stage 4: out = y @ Wo + bo
    gemm128<1><<<dim3(8, 64), blk, 0, stream>>>(y, Wo, bo, out,
                                                BB * LL, DD, HH * HD);
}

// Round 2
// 254.644 us; speedup vs baseline: 4.6916x; 4.6916x over previous
//
#include <hip/hip_runtime.h>
#include <hip/hip_bf16.h>

// B=4, L=2048, D=1024, H=16, HD=64, K=32, MAXLEN=2048
#define BB 4
#define LL 2048
#define DD 1024
#define HH 16
#define HD 64
#define KK 32

typedef __bf16 bf16x8 __attribute__((ext_vector_type(8)));
typedef __bf16 bf16x4 __attribute__((ext_vector_type(4)));
typedef float f32x4 __attribute__((ext_vector_type(4)));

// async global->LDS, 16B per lane; LDS dest = wave-uniform base + lane*16
__device__ inline void gl_lds16(const __bf16* g, __bf16* l) {
    __builtin_amdgcn_global_load_lds((const __attribute__((address_space(1))) void*)g,
                                     (__attribute__((address_space(3))) void*)l, 16, 0, 0);
}

// ---------------------------------------------------------------------------
// elementwise fp32 -> bf16 cast, 8 elems/thread
// ---------------------------------------------------------------------------
__global__ __launch_bounds__(256) void cast_bf16(const float* __restrict__ in,
                                                 __bf16* __restrict__ out) {
    const int t = blockIdx.x * 256 + threadIdx.x;
    const float4* in4 = (const float4*)in;
    float4 f0 = in4[t * 2], f1 = in4[t * 2 + 1];
    bf16x8 o;
    o[0] = (__bf16)f0.x; o[1] = (__bf16)f0.y; o[2] = (__bf16)f0.z; o[3] = (__bf16)f0.w;
    o[4] = (__bf16)f1.x; o[5] = (__bf16)f1.y; o[6] = (__bf16)f1.z; o[7] = (__bf16)f1.w;
    *(bf16x8*)&out[(size_t)t * 8] = o;
}

// ---------------------------------------------------------------------------
// fp32 [R][C] -> bf16 [C][R] transpose+cast, 32x64 tile per block, batched (z)
// ---------------------------------------------------------------------------
__global__ __launch_bounds__(256) void transpose_cast(const float* __restrict__ in,
                                                      __bf16* __restrict__ out,
                                                      int R, int C, long ibs, long obs) {
    __shared__ float Ls[32][65];
    in += (size_t)blockIdx.z * ibs;
    out += (size_t)blockIdx.z * obs;
    const int tid = threadIdx.x;
    const int r0 = blockIdx.y * 32, c0 = blockIdx.x * 64;
#pragma unroll
    for (int p = 0; p < 2; ++p) {
        int f = tid + 256 * p;
        int row = f >> 4, c4 = (f & 15) << 2;
        float4 v = *(const float4*)&in[(size_t)(r0 + row) * C + c0 + c4];
        Ls[row][c4 + 0] = v.x; Ls[row][c4 + 1] = v.y;
        Ls[row][c4 + 2] = v.z; Ls[row][c4 + 3] = v.w;
    }
    __syncthreads();
    const int orow = tid >> 2, rc = (tid & 3) << 3;
    bf16x8 o;
#pragma unroll
    for (int j = 0; j < 8; ++j) o[j] = (__bf16)Ls[rc + j][orow];
    *(bf16x8*)&out[(size_t)(c0 + orow) * R + r0 + rc] = o;
}

// ---------------------------------------------------------------------------
// bf16 MFMA GEMM (m97 recipe): C = A(MxK) @ Bt(NxK)^T + bias[col].
// 128x128 tile, BK=32, 4 waves in 2x2, 4x4 16x16x32 MFMAs per wave.
// MODE 0: write bf16 V2t[h][b*64+hd][n]  (row=(b,n), col=(h,hd))
// MODE 1: write fp32 C[row][col]
// ---------------------------------------------------------------------------
template <int MODE>
__global__ __launch_bounds__(256) void gemm_bt(const __bf16* __restrict__ A,
                                               const __bf16* __restrict__ Bt,
                                               const float* __restrict__ bias,
                                               void* __restrict__ Cout,
                                               int M, int N, int K) {
    __shared__ alignas(16) __bf16 As[128 * 32];
    __shared__ alignas(16) __bf16 Bs[128 * 32];
    const int tid = threadIdx.x;
    const int lane = tid & 63;
    const int wid = __builtin_amdgcn_readfirstlane(tid >> 6);
    const int row0 = blockIdx.y * 128, col0 = blockIdx.x * 128;
    const int l15 = lane & 15, quad = lane >> 4;
    const int wr = wid & 1, wc = wid >> 1;
    const int s0 = wid * 2, s1 = s0 + 1;

    const __bf16* ga0 = A + (size_t)(row0 + s0 * 16 + (lane >> 2)) * K + ((lane & 3) << 3);
    const __bf16* ga1 = ga0 + (size_t)16 * K;
    const __bf16* gb0 = Bt + (size_t)(col0 + s0 * 16 + (lane >> 2)) * K + ((lane & 3) << 3);
    const __bf16* gb1 = gb0 + (size_t)16 * K;
    __bf16* la0 = As + s0 * 512;
    __bf16* la1 = As + s1 * 512;
    __bf16* lb0 = Bs + s0 * 512;
    __bf16* lb1 = Bs + s1 * 512;

    f32x4 acc[4][4];
#pragma unroll
    for (int i = 0; i < 4; ++i)
#pragma unroll
        for (int j = 0; j < 4; ++j) acc[i][j] = (f32x4){0.f, 0.f, 0.f, 0.f};

    for (int k0 = 0; k0 < K; k0 += 32) {
        __syncthreads();
        gl_lds16(ga0 + k0, la0);
        gl_lds16(ga1 + k0, la1);
        gl_lds16(gb0 + k0, lb0);
        gl_lds16(gb1 + k0, lb1);
        __syncthreads();
        bf16x8 af[4], bfv[4];
#pragma unroll
        for (int i = 0; i < 4; ++i)
            af[i] = *(const bf16x8*)&As[(wr * 64 + i * 16 + l15) * 32 + quad * 8];
#pragma unroll
        for (int j = 0; j < 4; ++j)
            bfv[j] = *(const bf16x8*)&Bs[(wc * 64 + j * 16 + l15) * 32 + quad * 8];
#pragma unroll
        for (int i = 0; i < 4; ++i)
#pragma unroll
            for (int j = 0; j < 4; ++j)
                acc[i][j] = __builtin_amdgcn_mfma_f32_16x16x32_bf16(af[i], bfv[j], acc[i][j], 0, 0, 0);
    }

#pragma unroll
    for (int i = 0; i < 4; ++i) {
        const int rg = row0 + wr * 64 + i * 16 + quad * 4;  // rows rg..rg+3
#pragma unroll
        for (int j = 0; j < 4; ++j) {
            const int cg = col0 + wc * 64 + j * 16 + l15;
            const float bb = bias[cg];
            if (MODE == 0) {
                const int b = rg >> 11, n = rg & 2047;
                const int h = cg >> 6, hd = cg & 63;
                __bf16* V2t = (__bf16*)Cout;
                bf16x4 v;
#pragma unroll
                for (int r = 0; r < 4; ++r) v[r] = (__bf16)(acc[i][j][r] + bb);
                *(bf16x4*)&V2t[(size_t)(h * 256 + b * 64 + hd) * 2048 + n] = v;
            } else {
                float* Cf = (float*)Cout;
#pragma unroll
                for (int r = 0; r < 4; ++r)
                    Cf[(size_t)(rg + r) * N + cg] = acc[i][j][r] + bb;
            }
        }
    }
}

// ---------------------------------------------------------------------------
// Fused synthetic attention: per (h, 64 l-rows) block, loop n-chunks of 64:
//   S = r1 @ r2t^T (MFMA) -> e = exp(S) (scores tiny: no max needed)
//   -> P(bf16) to LDS (A-layout round-trip), denom accumulates in regs
//   -> y += P @ V2t^T (MFMA).  Normalize by 1/denom at the end.
// Wave w owns c-strip [w*64, w*64+64) => b = w.  Writes yb[b][l][h*64+hd] bf16.
// ---------------------------------------------------------------------------
__global__ __launch_bounds__(256) void attn_pv_mfma(const __bf16* __restrict__ r1b,
                                                    const __bf16* __restrict__ r2t,
                                                    const __bf16* __restrict__ V2t,
                                                    __bf16* __restrict__ yb) {
    __shared__ alignas(16) __bf16 r1s[64 * 32];
    __shared__ alignas(16) __bf16 r2s[64 * 32];
    __shared__ alignas(16) __bf16 Ps[64 * 72];     // rows padded to 72
    __shared__ alignas(16) __bf16 V2s[256 * 64];
    __shared__ float invd[64];
    const int tid = threadIdx.x;
    const int lane = tid & 63;
    const int wid = __builtin_amdgcn_readfirstlane(tid >> 6);
    const int l15 = lane & 15, quad = lane >> 4;
    const int id = blockIdx.x;
    const int h = id & 15;            // id%8 == h%8 -> per-XCD head locality
    const int l0 = (id >> 4) << 6;

    gl_lds16(r1b + (size_t)(h * 2048 + l0 + wid * 16 + (lane >> 2)) * 32 + ((lane & 3) << 3),
             r1s + wid * 512);
    const __bf16* gr2 = r2t + (size_t)(h * 2048 + wid * 16 + (lane >> 2)) * 32 + ((lane & 3) << 3);
    const __bf16* gv0 = V2t + (size_t)(h * 256 + wid * 64 + (lane >> 3)) * 2048 + ((lane & 7) << 3);

    __syncthreads();
    const bf16x8 a_s = *(const bf16x8*)&r1s[(wid * 16 + l15) * 32 + quad * 8];

    f32x4 acc[4][4];
#pragma unroll
    for (int i = 0; i < 4; ++i)
#pragma unroll
        for (int j = 0; j < 4; ++j) acc[i][j] = (f32x4){0.f, 0.f, 0.f, 0.f};
    float dsum[4] = {0.f, 0.f, 0.f, 0.f};
    const f32x4 zero4 = {0.f, 0.f, 0.f, 0.f};

    for (int n0 = 0; n0 < LL; n0 += 64) {
        __syncthreads();
        gl_lds16(gr2 + (size_t)n0 * 32, r2s + wid * 512);
#pragma unroll
        for (int p = 0; p < 8; ++p)
            gl_lds16(gv0 + (size_t)p * 8 * 2048 + n0, V2s + (wid * 8 + p) * 512);
        __syncthreads();
        // scores for l-strip [wid*16,+16)
#pragma unroll
        for (int j = 0; j < 4; ++j) {
            bf16x8 b = *(const bf16x8*)&r2s[(j * 16 + l15) * 32 + quad * 8];
            f32x4 s = __builtin_amdgcn_mfma_f32_16x16x32_bf16(a_s, b, zero4, 0, 0, 0);
#pragma unroll
            for (int r = 0; r < 4; ++r) {
                float e = __expf(s[r]);
                dsum[r] += e;
                Ps[(wid * 16 + quad * 4 + r) * 72 + j * 16 + l15] = (__bf16)e;
            }
        }
        __syncthreads();
        // y += P @ V
#pragma unroll
        for (int ks = 0; ks < 2; ++ks) {
            bf16x8 pa[4];
#pragma unroll
            for (int i = 0; i < 4; ++i)
                pa[i] = *(const bf16x8*)&Ps[(i * 16 + l15) * 72 + ks * 32 + quad * 8];
#pragma unroll
            for (int j = 0; j < 4; ++j) {
                bf16x8 vb = *(const bf16x8*)&V2s[(wid * 64 + j * 16 + l15) * 64 + ks * 32 + quad * 8];
#pragma unroll
                for (int i = 0; i < 4; ++i)
                    acc[i][j] = __builtin_amdgcn_mfma_f32_16x16x32_bf16(pa[i], vb, acc[i][j], 0, 0, 0);
            }
        }
    }
    // denominators: reduce over the 16 n-lanes (fp32, pre-bf16-rounding)
#pragma unroll
    for (int r = 0; r < 4; ++r) {
        float v = dsum[r];
        v += __shfl_xor(v, 1);
        v += __shfl_xor(v, 2);
        v += __shfl_xor(v, 4);
        v += __shfl_xor(v, 8);
        if (l15 == 0) invd[wid * 16 + quad * 4 + r] = 1.0f / v;
    }
    __syncthreads();
#pragma unroll
    for (int i = 0; i < 4; ++i) {
#pragma unroll
        for (int r = 0; r < 4; ++r) {
            const int l = i * 16 + quad * 4 + r;
            const float iv = invd[l];
            const size_t rowbase = ((size_t)wid * LL + l0 + l) * 1024 + h * 64;
#pragma unroll
            for (int j = 0; j < 4; ++j)
                yb[rowbase + j * 16 + l15] = (__bf16)(acc[i][j][r] * iv);
        }
    }
}

extern "C" void kernel_launch(void* const* d_in, const int* in_sizes, int n_in,
                              void* d_out, int out_size, void* d_ws, size_t ws_size,
                              hipStream_t stream) {
    const float* inputs_kv = (const float*)d_in[1];
    const float* Wv = (const float*)d_in[2];   // (D, H*HD)
    const float* bv = (const float*)d_in[3];   // (H*HD)
    const float* r1 = (const float*)d_in[4];   // (H, L, K)
    const float* r2 = (const float*)d_in[5];   // (H, K, L)
    const float* Wo = (const float*)d_in[6];   // (H*HD, D)
    const float* bo = (const float*)d_in[7];   // (D)
    float* out = (float*)d_out;

    char* ws = (char*)d_ws;
    const size_t MB = 1024 * 1024;
    __bf16* A1  = (__bf16*)(ws);             // 16 MB  bf16(inputs_kv) [8192][1024]
    __bf16* Wvt = (__bf16*)(ws + 16 * MB);   //  2 MB  Wv^T  [c'][d]
    __bf16* Wot = (__bf16*)(ws + 18 * MB);   //  2 MB  Wo^T  [d][c']
    __bf16* r1b = (__bf16*)(ws + 20 * MB);   //  2 MB  bf16(r1) [h][l][32]
    __bf16* r2t = (__bf16*)(ws + 22 * MB);   //  2 MB  r2^T per head [h][n][32]
    __bf16* V2t = (__bf16*)(ws + 24 * MB);   // 16 MB  V [h][b*64+hd][n]
    __bf16* yb  = (__bf16*)(ws + 40 * MB);   // 16 MB  y [b][l][h*64+hd]

    cast_bf16<<<4096, 256, 0, stream>>>(inputs_kv, A1);
    cast_bf16<<<512, 256, 0, stream>>>(r1, r1b);
    transpose_cast<<<dim3(16, 32, 1), 256, 0, stream>>>(Wv, Wvt, 1024, 1024, 0, 0);
    transpose_cast<<<dim3(16, 32, 1), 256, 0, stream>>>(Wo, Wot, 1024, 1024, 0, 0);
    transpose_cast<<<dim3(32, 1, 16), 256, 0, stream>>>(r2, r2t, 32, 2048,
                                                        (long)32 * 2048, (long)2048 * 32);
    gemm_bt<0><<<dim3(8, 64), 256, 0, stream>>>(A1, Wvt, bv, V2t, 8192, 1024, 1024);
    attn_pv_mfma<<<512, 256, 0, stream>>>(r1b, r2t, V2t, yb);
    gemm_bt<1><<<dim3(8, 64), 256, 0, stream>>>(yb, Wot, bo, out, 8192, 1024, 1024);
}

// Round 3
// 245.262 us; speedup vs baseline: 4.8711x; 1.0383x over previous
//
#include <hip/hip_runtime.h>
#include <hip/hip_bf16.h>

// B=4, L=2048, D=1024, H=16, HD=64, K=32, MAXLEN=2048
#define LL 2048

typedef __bf16 bf16x8 __attribute__((ext_vector_type(8)));
typedef __bf16 bf16x4 __attribute__((ext_vector_type(4)));
typedef float f32x4 __attribute__((ext_vector_type(4)));

// async global->LDS, 16B per lane; LDS dest = wave-uniform base + lane*16
__device__ inline void gl_lds16(const __bf16* g, __bf16* l) {
    __builtin_amdgcn_global_load_lds((const __attribute__((address_space(1))) void*)g,
                                     (__attribute__((address_space(3))) void*)l, 16, 0, 0);
}

// ---------------------------------------------------------------------------
// Unified prep: blocks [0,4096) cast inputs_kv->A1; [4096,4608) cast r1->r1b;
// [4608,5120) transpose Wv; [5120,5632) transpose Wo; [5632,6144) transpose r2
// (per-head 32x2048 -> 2048x32).
// ---------------------------------------------------------------------------
__global__ __launch_bounds__(256) void prep(const float* __restrict__ inputs_kv,
                                            const float* __restrict__ r1,
                                            const float* __restrict__ Wv,
                                            const float* __restrict__ Wo,
                                            const float* __restrict__ r2,
                                            __bf16* __restrict__ A1,
                                            __bf16* __restrict__ r1b,
                                            __bf16* __restrict__ Wvt,
                                            __bf16* __restrict__ Wot,
                                            __bf16* __restrict__ r2t) {
    __shared__ float Ls[32][65];
    int bid = blockIdx.x;
    const int tid = threadIdx.x;
    if (bid < 4608) {
        const float* in = (bid < 4096) ? inputs_kv : r1;
        __bf16* out = (bid < 4096) ? A1 : r1b;
        const int t = ((bid < 4096) ? bid : bid - 4096) * 256 + tid;
        const float4* in4 = (const float4*)in;
        float4 f0 = in4[t * 2], f1 = in4[t * 2 + 1];
        bf16x8 o;
        o[0] = (__bf16)f0.x; o[1] = (__bf16)f0.y; o[2] = (__bf16)f0.z; o[3] = (__bf16)f0.w;
        o[4] = (__bf16)f1.x; o[5] = (__bf16)f1.y; o[6] = (__bf16)f1.z; o[7] = (__bf16)f1.w;
        *(bf16x8*)&out[(size_t)t * 8] = o;
        return;
    }
    bid -= 4608;
    const float* in;
    __bf16* out;
    int R, C, r0, c0;
    if (bid < 512) {
        in = Wv; out = Wvt; R = 1024; C = 1024;
        c0 = (bid & 15) * 64; r0 = (bid >> 4) * 32;
    } else if (bid < 1024) {
        bid -= 512;
        in = Wo; out = Wot; R = 1024; C = 1024;
        c0 = (bid & 15) * 64; r0 = (bid >> 4) * 32;
    } else {
        bid -= 1024;
        const int bz = bid >> 5;
        in = r2 + (size_t)bz * 65536; out = r2t + (size_t)bz * 65536;
        R = 32; C = 2048;
        c0 = (bid & 31) * 64; r0 = 0;
    }
#pragma unroll
    for (int p = 0; p < 2; ++p) {
        int f = tid + 256 * p;
        int row = f >> 4, c4 = (f & 15) << 2;
        float4 v = *(const float4*)&in[(size_t)(r0 + row) * C + c0 + c4];
        Ls[row][c4 + 0] = v.x; Ls[row][c4 + 1] = v.y;
        Ls[row][c4 + 2] = v.z; Ls[row][c4 + 3] = v.w;
    }
    __syncthreads();
    const int orow = tid >> 2, rc = (tid & 3) << 3;
    bf16x8 o;
#pragma unroll
    for (int j = 0; j < 8; ++j) o[j] = (__bf16)Ls[rc + j][orow];
    *(bf16x8*)&out[(size_t)(c0 + orow) * R + r0 + rc] = o;
}

// ---------------------------------------------------------------------------
// bf16 MFMA GEMM (m97 recipe, unchanged from R2): C = A(MxK) @ Bt(NxK)^T + bias.
// MODE 0: write bf16 V2t[h][b*64+hd][n]; MODE 1: write fp32 C[row][col]
// ---------------------------------------------------------------------------
template <int MODE>
__global__ __launch_bounds__(256) void gemm_bt(const __bf16* __restrict__ A,
                                               const __bf16* __restrict__ Bt,
                                               const float* __restrict__ bias,
                                               void* __restrict__ Cout,
                                               int M, int N, int K) {
    __shared__ alignas(16) __bf16 As[128 * 32];
    __shared__ alignas(16) __bf16 Bs[128 * 32];
    const int tid = threadIdx.x;
    const int lane = tid & 63;
    const int wid = __builtin_amdgcn_readfirstlane(tid >> 6);
    const int row0 = blockIdx.y * 128, col0 = blockIdx.x * 128;
    const int l15 = lane & 15, quad = lane >> 4;
    const int wr = wid & 1, wc = wid >> 1;
    const int s0 = wid * 2, s1 = s0 + 1;

    const __bf16* ga0 = A + (size_t)(row0 + s0 * 16 + (lane >> 2)) * K + ((lane & 3) << 3);
    const __bf16* ga1 = ga0 + (size_t)16 * K;
    const __bf16* gb0 = Bt + (size_t)(col0 + s0 * 16 + (lane >> 2)) * K + ((lane & 3) << 3);
    const __bf16* gb1 = gb0 + (size_t)16 * K;
    __bf16* la0 = As + s0 * 512;
    __bf16* la1 = As + s1 * 512;
    __bf16* lb0 = Bs + s0 * 512;
    __bf16* lb1 = Bs + s1 * 512;

    f32x4 acc[4][4];
#pragma unroll
    for (int i = 0; i < 4; ++i)
#pragma unroll
        for (int j = 0; j < 4; ++j) acc[i][j] = (f32x4){0.f, 0.f, 0.f, 0.f};

    for (int k0 = 0; k0 < K; k0 += 32) {
        __syncthreads();
        gl_lds16(ga0 + k0, la0);
        gl_lds16(ga1 + k0, la1);
        gl_lds16(gb0 + k0, lb0);
        gl_lds16(gb1 + k0, lb1);
        __syncthreads();
        bf16x8 af[4], bfv[4];
#pragma unroll
        for (int i = 0; i < 4; ++i)
            af[i] = *(const bf16x8*)&As[(wr * 64 + i * 16 + l15) * 32 + quad * 8];
#pragma unroll
        for (int j = 0; j < 4; ++j)
            bfv[j] = *(const bf16x8*)&Bs[(wc * 64 + j * 16 + l15) * 32 + quad * 8];
#pragma unroll
        for (int i = 0; i < 4; ++i)
#pragma unroll
            for (int j = 0; j < 4; ++j)
                acc[i][j] = __builtin_amdgcn_mfma_f32_16x16x32_bf16(af[i], bfv[j], acc[i][j], 0, 0, 0);
    }

#pragma unroll
    for (int i = 0; i < 4; ++i) {
        const int rg = row0 + wr * 64 + i * 16 + quad * 4;  // rows rg..rg+3
#pragma unroll
        for (int j = 0; j < 4; ++j) {
            const int cg = col0 + wc * 64 + j * 16 + l15;
            const float bb = bias[cg];
            if (MODE == 0) {
                const int b = rg >> 11, n = rg & 2047;
                const int h = cg >> 6, hd = cg & 63;
                __bf16* V2t = (__bf16*)Cout;
                bf16x4 v;
#pragma unroll
                for (int r = 0; r < 4; ++r) v[r] = (__bf16)(acc[i][j][r] + bb);
                *(bf16x4*)&V2t[(size_t)(h * 256 + b * 64 + hd) * 2048 + n] = v;
            } else {
                float* Cf = (float*)Cout;
#pragma unroll
                for (int r = 0; r < 4; ++r)
                    Cf[(size_t)(rg + r) * N + cg] = acc[i][j][r] + bb;
            }
        }
    }
}

// ---------------------------------------------------------------------------
// attn v3: S^T-orientation scores; r1/r2/V as direct-global register frags
// (no LDS staging -- V and r2 have zero cross-wave reuse); only P crosses
// waves via a double-buffered 9KB LDS tile; ONE barrier per 64-n chunk.
//   scores: S^T = mfma(A=r2t_frag, B=r1_frag)  -> lane holds 4 consecutive n
//   exp -> bf16x4 Ps writes -> barrier -> pa b128 reads -> 32 PV MFMAs.
// Wave w owns c-strip [w*64,+64) => b = w. Writes yb[b][l][h*64+hd] bf16.
// ---------------------------------------------------------------------------
__global__ __launch_bounds__(256) void attn_pv_v3(const __bf16* __restrict__ r1b,
                                                  const __bf16* __restrict__ r2t,
                                                  const __bf16* __restrict__ V2t,
                                                  __bf16* __restrict__ yb) {
    __shared__ alignas(16) __bf16 Ps[2][64 * 72];
    __shared__ float dpart[4][64];
    __shared__ float invd[64];
    const int tid = threadIdx.x;
    const int lane = tid & 63;
    const int wid = __builtin_amdgcn_readfirstlane(tid >> 6);
    const int l15 = lane & 15, quad = lane >> 4;
    const int id = blockIdx.x;
    const int h = id & 15;             // id%8 == h%8 -> per-XCD head locality
    const int l0 = (id >> 4) << 6;

    // r1 "B-frags" (bit-identical to A-frag loads), fixed for the block
    bf16x8 bf1[4];
#pragma unroll
    for (int i = 0; i < 4; ++i)
        bf1[i] = *(const bf16x8*)&r1b[(size_t)(h * 2048 + l0 + i * 16 + l15) * 32 + quad * 8];

    const __bf16* r2base = r2t + (size_t)(h * 2048 + wid * 16 + l15) * 32 + quad * 8;
    const __bf16* vbase = V2t + (size_t)(h * 256 + wid * 64 + l15) * 2048 + quad * 8;

    // chunk-0 prefetch
    bf16x8 r2pf = *(const bf16x8*)r2base;
    bf16x8 vpf[4][2];
#pragma unroll
    for (int jt = 0; jt < 4; ++jt)
#pragma unroll
        for (int ks = 0; ks < 2; ++ks)
            vpf[jt][ks] = *(const bf16x8*)(vbase + jt * 32768 + ks * 32);

    f32x4 acc[4][4];
#pragma unroll
    for (int i = 0; i < 4; ++i)
#pragma unroll
        for (int j = 0; j < 4; ++j) acc[i][j] = (f32x4){0.f, 0.f, 0.f, 0.f};
    float dsum[4] = {0.f, 0.f, 0.f, 0.f};
    const f32x4 zero4 = {0.f, 0.f, 0.f, 0.f};

    for (int c = 0; c < 32; ++c) {
        const int npf = ((c + 1) & 31) << 6;   // next chunk base (wraps; harmless)
        // scores S^T for this wave's 16-n strip, all 64 l
        f32x4 s[4];
#pragma unroll
        for (int i = 0; i < 4; ++i)
            s[i] = __builtin_amdgcn_mfma_f32_16x16x32_bf16(r2pf, bf1[i], zero4, 0, 0, 0);
        r2pf = *(const bf16x8*)(r2base + (size_t)npf * 32);   // prefetch next
        // exp -> pack -> Ps ; lane holds P[l=i*16+l15][n = wid*16+quad*4+r]
        __bf16* ps = Ps[c & 1];
#pragma unroll
        for (int i = 0; i < 4; ++i) {
            float e0 = __expf(s[i][0]), e1 = __expf(s[i][1]);
            float e2 = __expf(s[i][2]), e3 = __expf(s[i][3]);
            dsum[i] += (e0 + e1) + (e2 + e3);
            bf16x4 p4;
            p4[0] = (__bf16)e0; p4[1] = (__bf16)e1;
            p4[2] = (__bf16)e2; p4[3] = (__bf16)e3;
            *(bf16x4*)&ps[(i * 16 + l15) * 72 + wid * 16 + quad * 4] = p4;
        }
        __syncthreads();
        bf16x8 pa[4][2];
#pragma unroll
        for (int i = 0; i < 4; ++i)
#pragma unroll
            for (int ks = 0; ks < 2; ++ks)
                pa[i][ks] = *(const bf16x8*)&ps[(i * 16 + l15) * 72 + ks * 32 + quad * 8];
        // PV: y[l][c] += P @ V (consume vpf), then prefetch next chunk's V
#pragma unroll
        for (int ks = 0; ks < 2; ++ks)
#pragma unroll
            for (int jt = 0; jt < 4; ++jt)
#pragma unroll
                for (int i = 0; i < 4; ++i)
                    acc[i][jt] = __builtin_amdgcn_mfma_f32_16x16x32_bf16(pa[i][ks], vpf[jt][ks],
                                                                         acc[i][jt], 0, 0, 0);
#pragma unroll
        for (int jt = 0; jt < 4; ++jt)
#pragma unroll
            for (int ks = 0; ks < 2; ++ks)
                vpf[jt][ks] = *(const bf16x8*)(vbase + jt * 32768 + npf + ks * 32);
    }

    // denominators: dsum[i] is this lane's partial for l = i*16+l15 over its
    // (wid, quad) n-subset; reduce over quad in-wave, over wid via LDS.
#pragma unroll
    for (int i = 0; i < 4; ++i) {
        float v = dsum[i];
        v += __shfl_xor(v, 16);
        v += __shfl_xor(v, 32);
        if (quad == 0) dpart[wid][i * 16 + l15] = v;
    }
    __syncthreads();
    if (tid < 64)
        invd[tid] = 1.0f / (dpart[0][tid] + dpart[1][tid] + dpart[2][tid] + dpart[3][tid]);
    __syncthreads();
#pragma unroll
    for (int i = 0; i < 4; ++i) {
#pragma unroll
        for (int r = 0; r < 4; ++r) {
            const int l = i * 16 + quad * 4 + r;
            const float iv = invd[l];
            const size_t rowbase = ((size_t)wid * LL + l0 + l) * 1024 + h * 64;
#pragma unroll
            for (int jt = 0; jt < 4; ++jt)
                yb[rowbase + jt * 16 + l15] = (__bf16)(acc[i][jt][r] * iv);
        }
    }
}

extern "C" void kernel_launch(void* const* d_in, const int* in_sizes, int n_in,
                              void* d_out, int out_size, void* d_ws, size_t ws_size,
                              hipStream_t stream) {
    const float* inputs_kv = (const float*)d_in[1];
    const float* Wv = (const float*)d_in[2];   // (D, H*HD)
    const float* bv = (const float*)d_in[3];   // (H*HD)
    const float* r1 = (const float*)d_in[4];   // (H, L, K)
    const float* r2 = (const float*)d_in[5];   // (H, K, L)
    const float* Wo = (const float*)d_in[6];   // (H*HD, D)
    const float* bo = (const float*)d_in[7];   // (D)
    float* out = (float*)d_out;

    char* ws = (char*)d_ws;
    const size_t MB = 1024 * 1024;
    __bf16* A1  = (__bf16*)(ws);             // 16 MB  bf16(inputs_kv) [8192][1024]
    __bf16* Wvt = (__bf16*)(ws + 16 * MB);   //  2 MB  Wv^T  [c'][d]
    __bf16* Wot = (__bf16*)(ws + 18 * MB);   //  2 MB  Wo^T  [d][c']
    __bf16* r1b = (__bf16*)(ws + 20 * MB);   //  2 MB  bf16(r1) [h][l][32]
    __bf16* r2t = (__bf16*)(ws + 22 * MB);   //  2 MB  r2^T per head [h][n][32]
    __bf16* V2t = (__bf16*)(ws + 24 * MB);   // 16 MB  V [h][b*64+hd][n]
    __bf16* yb  = (__bf16*)(ws + 40 * MB);   // 16 MB  y [b][l][h*64+hd]

    prep<<<6144, 256, 0, stream>>>(inputs_kv, r1, Wv, Wo, r2, A1, r1b, Wvt, Wot, r2t);
    gemm_bt<0><<<dim3(8, 64), 256, 0, stream>>>(A1, Wvt, bv, V2t, 8192, 1024, 1024);
    attn_pv_v3<<<512, 256, 0, stream>>>(r1b, r2t, V2t, yb);
    gemm_bt<1><<<dim3(8, 64), 256, 0, stream>>>(yb, Wot, bo, out, 8192, 1024, 1024);
}

// Round 4
// 220.738 us; speedup vs baseline: 5.4122x; 1.1111x over previous
//
#include <hip/hip_runtime.h>
#include <hip/hip_bf16.h>

// B=4, L=2048, D=1024, H=16, HD=64, K=32, MAXLEN=2048
#define LL 2048

typedef __bf16 bf16x8 __attribute__((ext_vector_type(8)));
typedef __bf16 bf16x4 __attribute__((ext_vector_type(4)));
typedef float f32x4 __attribute__((ext_vector_type(4)));

// async global->LDS, 16B per lane; LDS dest = wave-uniform base + lane*16
__device__ inline void gl_lds16(const __bf16* g, __bf16* l) {
    __builtin_amdgcn_global_load_lds((const __attribute__((address_space(1))) void*)g,
                                     (__attribute__((address_space(3))) void*)l, 16, 0, 0);
}

// ---------------------------------------------------------------------------
// Unified prep: blocks [0,4096) cast inputs_kv->A1; [4096,4608) cast r1->r1b;
// [4608,5120) transpose Wv; [5120,5632) transpose Wo; [5632,6144) transpose r2.
// ---------------------------------------------------------------------------
__global__ __launch_bounds__(256) void prep(const float* __restrict__ inputs_kv,
                                            const float* __restrict__ r1,
                                            const float* __restrict__ Wv,
                                            const float* __restrict__ Wo,
                                            const float* __restrict__ r2,
                                            __bf16* __restrict__ A1,
                                            __bf16* __restrict__ r1b,
                                            __bf16* __restrict__ Wvt,
                                            __bf16* __restrict__ Wot,
                                            __bf16* __restrict__ r2t) {
    __shared__ float Ls[32][65];
    int bid = blockIdx.x;
    const int tid = threadIdx.x;
    if (bid < 4608) {
        const float* in = (bid < 4096) ? inputs_kv : r1;
        __bf16* out = (bid < 4096) ? A1 : r1b;
        const int t = ((bid < 4096) ? bid : bid - 4096) * 256 + tid;
        const float4* in4 = (const float4*)in;
        float4 f0 = in4[t * 2], f1 = in4[t * 2 + 1];
        bf16x8 o;
        o[0] = (__bf16)f0.x; o[1] = (__bf16)f0.y; o[2] = (__bf16)f0.z; o[3] = (__bf16)f0.w;
        o[4] = (__bf16)f1.x; o[5] = (__bf16)f1.y; o[6] = (__bf16)f1.z; o[7] = (__bf16)f1.w;
        *(bf16x8*)&out[(size_t)t * 8] = o;
        return;
    }
    bid -= 4608;
    const float* in;
    __bf16* out;
    int R, C, r0, c0;
    if (bid < 512) {
        in = Wv; out = Wvt; R = 1024; C = 1024;
        c0 = (bid & 15) * 64; r0 = (bid >> 4) * 32;
    } else if (bid < 1024) {
        bid -= 512;
        in = Wo; out = Wot; R = 1024; C = 1024;
        c0 = (bid & 15) * 64; r0 = (bid >> 4) * 32;
    } else {
        bid -= 1024;
        const int bz = bid >> 5;
        in = r2 + (size_t)bz * 65536; out = r2t + (size_t)bz * 65536;
        R = 32; C = 2048;
        c0 = (bid & 31) * 64; r0 = 0;
    }
#pragma unroll
    for (int p = 0; p < 2; ++p) {
        int f = tid + 256 * p;
        int row = f >> 4, c4 = (f & 15) << 2;
        float4 v = *(const float4*)&in[(size_t)(r0 + row) * C + c0 + c4];
        Ls[row][c4 + 0] = v.x; Ls[row][c4 + 1] = v.y;
        Ls[row][c4 + 2] = v.z; Ls[row][c4 + 3] = v.w;
    }
    __syncthreads();
    const int orow = tid >> 2, rc = (tid & 3) << 3;
    bf16x8 o;
#pragma unroll
    for (int j = 0; j < 8; ++j) o[j] = (__bf16)Ls[rc + j][orow];
    *(bf16x8*)&out[(size_t)(c0 + orow) * R + r0 + rc] = o;
}

// ---------------------------------------------------------------------------
// bf16 MFMA GEMM (m97 recipe): C = A(MxK) @ Bt(NxK)^T + bias.
// MODE 0: scatter bf16 V into FRAGMENT-MAJOR layout V3:
//   tile(h, nc=n>>6, b) of 4096 elems at ((h*32+nc)*4+b)*4096;
//   within tile: frag(jt=hd>>4, ks=(n>>5)&1)*512 + (hd&15)*32 + ((n>>3)&3)*8 + (n&7)
//   -> every attn B-frag load is 64 lanes x 16B CONTIGUOUS (1KB).
// MODE 1: write fp32 C[row][col]
// ---------------------------------------------------------------------------
template <int MODE>
__global__ __launch_bounds__(256) void gemm_bt(const __bf16* __restrict__ A,
                                               const __bf16* __restrict__ Bt,
                                               const float* __restrict__ bias,
                                               void* __restrict__ Cout,
                                               int M, int N, int K) {
    __shared__ alignas(16) __bf16 As[128 * 32];
    __shared__ alignas(16) __bf16 Bs[128 * 32];
    const int tid = threadIdx.x;
    const int lane = tid & 63;
    const int wid = __builtin_amdgcn_readfirstlane(tid >> 6);
    const int row0 = blockIdx.y * 128, col0 = blockIdx.x * 128;
    const int l15 = lane & 15, quad = lane >> 4;
    const int wr = wid & 1, wc = wid >> 1;
    const int s0 = wid * 2, s1 = s0 + 1;

    const __bf16* ga0 = A + (size_t)(row0 + s0 * 16 + (lane >> 2)) * K + ((lane & 3) << 3);
    const __bf16* ga1 = ga0 + (size_t)16 * K;
    const __bf16* gb0 = Bt + (size_t)(col0 + s0 * 16 + (lane >> 2)) * K + ((lane & 3) << 3);
    const __bf16* gb1 = gb0 + (size_t)16 * K;
    __bf16* la0 = As + s0 * 512;
    __bf16* la1 = As + s1 * 512;
    __bf16* lb0 = Bs + s0 * 512;
    __bf16* lb1 = Bs + s1 * 512;

    f32x4 acc[4][4];
#pragma unroll
    for (int i = 0; i < 4; ++i)
#pragma unroll
        for (int j = 0; j < 4; ++j) acc[i][j] = (f32x4){0.f, 0.f, 0.f, 0.f};

    for (int k0 = 0; k0 < K; k0 += 32) {
        __syncthreads();
        gl_lds16(ga0 + k0, la0);
        gl_lds16(ga1 + k0, la1);
        gl_lds16(gb0 + k0, lb0);
        gl_lds16(gb1 + k0, lb1);
        __syncthreads();
        bf16x8 af[4], bfv[4];
#pragma unroll
        for (int i = 0; i < 4; ++i)
            af[i] = *(const bf16x8*)&As[(wr * 64 + i * 16 + l15) * 32 + quad * 8];
#pragma unroll
        for (int j = 0; j < 4; ++j)
            bfv[j] = *(const bf16x8*)&Bs[(wc * 64 + j * 16 + l15) * 32 + quad * 8];
#pragma unroll
        for (int i = 0; i < 4; ++i)
#pragma unroll
            for (int j = 0; j < 4; ++j)
                acc[i][j] = __builtin_amdgcn_mfma_f32_16x16x32_bf16(af[i], bfv[j], acc[i][j], 0, 0, 0);
    }

#pragma unroll
    for (int i = 0; i < 4; ++i) {
        const int rg = row0 + wr * 64 + i * 16 + quad * 4;  // rows rg..rg+3
#pragma unroll
        for (int j = 0; j < 4; ++j) {
            const int cg = col0 + wc * 64 + j * 16 + l15;
            const float bb = bias[cg];
            if (MODE == 0) {
                const int b = rg >> 11, n = rg & 2047;     // 4 consecutive n
                const int h = cg >> 6, hd = cg & 63;
                const int nc = n >> 6, ks = (n >> 5) & 1, qj = (n >> 3) & 3, j0 = n & 7;
                const int jt = hd >> 4, fl = hd & 15;
                __bf16* V3 = (__bf16*)Cout;
                bf16x4 v;
#pragma unroll
                for (int r = 0; r < 4; ++r) v[r] = (__bf16)(acc[i][j][r] + bb);
                *(bf16x4*)&V3[(size_t)(((h * 32 + nc) * 4 + b) * 4096) +
                              (jt * 2 + ks) * 512 + fl * 32 + qj * 8 + j0] = v;
            } else {
                float* Cf = (float*)Cout;
#pragma unroll
                for (int r = 0; r < 4; ++r)
                    Cf[(size_t)(rg + r) * N + cg] = acc[i][j][r] + bb;
            }
        }
    }
}

// ---------------------------------------------------------------------------
// attn v4: 512 threads, 128 l-rows per block (grid 16h x 16 = 256 = 1/CU).
// Wave w: b-strip = w&3, l-half lh = w>>2. Per 64-n chunk:
//   wave computes S^T for n-strip (w&3)*16 x its 64 l (4 MFMAs, frags from
//   fully-coalesced global loads), exp -> bf16x4 -> frag-major Ps (LDS),
//   ONE barrier, pa b128 reads, 32 PV MFMAs from coalesced V3 frags
//   (+8 ones-MFMAs accumulate softmax denominators in C-layout).
// The two l-halves of a b-strip re-read the same 8KB V tile -> L1 hit.
// ---------------------------------------------------------------------------
__global__ __launch_bounds__(512) void attn_pv_v4(const __bf16* __restrict__ r1b,
                                                  const __bf16* __restrict__ r2t,
                                                  const __bf16* __restrict__ V3,
                                                  __bf16* __restrict__ yb) {
    __shared__ alignas(16) __bf16 Ps[2 * 2 * 4 * 1024];   // [buf][lh][i][ks*512+...] 32KB
    const int tid = threadIdx.x;
    const int lane = tid & 63;
    const int w = __builtin_amdgcn_readfirstlane(tid >> 6);
    const int b = w & 3, lh = w >> 2;
    const int l15 = lane & 15, quad = lane >> 4;
    const int id = blockIdx.x;
    const int h = id & 15;             // id%8 == h%8 -> per-XCD head locality
    const int l0 = (id >> 4) << 7;

    // r1 B-frags for this wave's 64 l (fixed)
    bf16x8 bf1[4];
#pragma unroll
    for (int i = 0; i < 4; ++i)
        bf1[i] = *(const bf16x8*)&r1b[(size_t)(h * 2048 + l0 + lh * 64 + i * 16 + l15) * 32 + quad * 8];

    const __bf16* r2p = r2t + (size_t)(h * 2048 + b * 16 + l15) * 32 + quad * 8;
    const __bf16* vp = V3 + (size_t)((h * 32) * 4 + b) * 4096 + l15 * 32 + quad * 8;

    // chunk-0 prefetch
    bf16x8 r2f = *(const bf16x8*)r2p;
    bf16x8 vpf[4][2];
#pragma unroll
    for (int jt = 0; jt < 4; ++jt)
#pragma unroll
        for (int ks = 0; ks < 2; ++ks)
            vpf[jt][ks] = *(const bf16x8*)(vp + (jt * 2 + ks) * 512);

    bf16x8 ones;
#pragma unroll
    for (int e = 0; e < 8; ++e) ones[e] = (__bf16)1.0f;

    f32x4 acc[4][4];
    f32x4 den[4];
#pragma unroll
    for (int i = 0; i < 4; ++i) {
        den[i] = (f32x4){0.f, 0.f, 0.f, 0.f};
#pragma unroll
        for (int j = 0; j < 4; ++j) acc[i][j] = (f32x4){0.f, 0.f, 0.f, 0.f};
    }
    const f32x4 zero4 = {0.f, 0.f, 0.f, 0.f};

    const int kw = b >> 1;                       // which ks this wave produces
    const int jg = (b & 1) * 2 + (quad >> 1);    // j-group within frag
    const int q4 = (quad & 1) * 4;

    for (int c = 0; c < 32; ++c) {
        const int cn = (c < 31) ? 1 : 0;         // last chunk: re-load (harmless)
        // scores S^T: rows = this wave's 16-n strip, cols = its 64 l
        f32x4 s[4];
#pragma unroll
        for (int i = 0; i < 4; ++i)
            s[i] = __builtin_amdgcn_mfma_f32_16x16x32_bf16(r2f, bf1[i], zero4, 0, 0, 0);
        r2f = *(const bf16x8*)(r2p + (size_t)cn * 2048);
        __bf16* ps = &Ps[((c & 1) * 2 + lh) * 4096];
#pragma unroll
        for (int i = 0; i < 4; ++i) {
            bf16x4 p4;
#pragma unroll
            for (int r = 0; r < 4; ++r) p4[r] = (__bf16)__expf(s[i][r]);
            *(bf16x4*)&ps[i * 1024 + kw * 512 + l15 * 32 + jg * 8 + q4] = p4;
        }
        __syncthreads();
        bf16x8 pa[4][2];
#pragma unroll
        for (int i = 0; i < 4; ++i)
#pragma unroll
            for (int ks = 0; ks < 2; ++ks)
                pa[i][ks] = *(const bf16x8*)&ps[i * 1024 + ks * 512 + l15 * 32 + quad * 8];
        // PV + denominators (consume vpf), then prefetch next chunk's V
#pragma unroll
        for (int ks = 0; ks < 2; ++ks) {
#pragma unroll
            for (int i = 0; i < 4; ++i) {
#pragma unroll
                for (int jt = 0; jt < 4; ++jt)
                    acc[i][jt] = __builtin_amdgcn_mfma_f32_16x16x32_bf16(pa[i][ks], vpf[jt][ks],
                                                                         acc[i][jt], 0, 0, 0);
                den[i] = __builtin_amdgcn_mfma_f32_16x16x32_bf16(pa[i][ks], ones, den[i], 0, 0, 0);
            }
        }
        vp += cn * 16384;
#pragma unroll
        for (int jt = 0; jt < 4; ++jt)
#pragma unroll
            for (int ks = 0; ks < 2; ++ks)
                vpf[jt][ks] = *(const bf16x8*)(vp + (jt * 2 + ks) * 512);
    }

    // epilogue: den[i][r] is the softmax denom for l = lh*64+i*16+quad*4+r (per-lane!)
#pragma unroll
    for (int i = 0; i < 4; ++i) {
#pragma unroll
        for (int r = 0; r < 4; ++r) {
            const float iv = 1.0f / den[i][r];
            const int l = l0 + lh * 64 + i * 16 + quad * 4 + r;
            const size_t rowbase = ((size_t)b * LL + l) * 1024 + h * 64;
#pragma unroll
            for (int jt = 0; jt < 4; ++jt)
                yb[rowbase + jt * 16 + l15] = (__bf16)(acc[i][jt][r] * iv);
        }
    }
}

extern "C" void kernel_launch(void* const* d_in, const int* in_sizes, int n_in,
                              void* d_out, int out_size, void* d_ws, size_t ws_size,
                              hipStream_t stream) {
    const float* inputs_kv = (const float*)d_in[1];
    const float* Wv = (const float*)d_in[2];   // (D, H*HD)
    const float* bv = (const float*)d_in[3];   // (H*HD)
    const float* r1 = (const float*)d_in[4];   // (H, L, K)
    const float* r2 = (const float*)d_in[5];   // (H, K, L)
    const float* Wo = (const float*)d_in[6];   // (H*HD, D)
    const float* bo = (const float*)d_in[7];   // (D)
    float* out = (float*)d_out;

    char* ws = (char*)d_ws;
    const size_t MB = 1024 * 1024;
    __bf16* A1  = (__bf16*)(ws);             // 16 MB  bf16(inputs_kv) [8192][1024]
    __bf16* Wvt = (__bf16*)(ws + 16 * MB);   //  2 MB  Wv^T
    __bf16* Wot = (__bf16*)(ws + 18 * MB);   //  2 MB  Wo^T
    __bf16* r1b = (__bf16*)(ws + 20 * MB);   //  2 MB  bf16(r1) [h][l][32]
    __bf16* r2t = (__bf16*)(ws + 22 * MB);   //  2 MB  r2^T per head [h][n][32]
    __bf16* V3  = (__bf16*)(ws + 24 * MB);   // 16 MB  V fragment-major (see gemm MODE 0)
    __bf16* yb  = (__bf16*)(ws + 40 * MB);   // 16 MB  y [b][l][h*64+hd]

    prep<<<6144, 256, 0, stream>>>(inputs_kv, r1, Wv, Wo, r2, A1, r1b, Wvt, Wot, r2t);
    gemm_bt<0><<<dim3(8, 64), 256, 0, stream>>>(A1, Wvt, bv, V3, 8192, 1024, 1024);
    attn_pv_v4<<<256, 512, 0, stream>>>(r1b, r2t, V3, yb);
    gemm_bt<1><<<dim3(8, 64), 256, 0, stream>>>(yb, Wot, bo, out, 8192, 1024, 1024);
}